// Round 3
// baseline (466.695 us; speedup 1.0000x reference)
//
#include <hip/hip_runtime.h>

// BlockResMLP MixerBlock: 2 layers of 64 independent block MLPs (64->128->64, ELU, residual)
// with a per-row 64x64 transpose (shuffle) around layer 2.
// bf16 MFMA (16x16x32 only, no inline asm), fp32 accumulate. 3 kernels:
//   k0: weight convert+transpose (LDS transpose, coalesced). Layer-1 weights get the
//       pi32 k-slot permutation so MFMA-transposed fragments consume them directly.
//   k1: layer-1 facto, writes y1 in granule-16 layout [row>>4][n][m][row&15].
//   k2: layer-2 facto + inverse shuffle + fp32 out. z- and h-transposes done with
//       permutation-B 16x16x32 MFMAs entirely in registers; residual reuses the z load
//       registers; only LDS use is a 37KB out-staging buffer with conflict-light strides.

typedef short short8 __attribute__((ext_vector_type(8)));
typedef short short4v __attribute__((ext_vector_type(4)));
typedef float floatx4 __attribute__((ext_vector_type(4)));
typedef unsigned int uintx4 __attribute__((ext_vector_type(4)));

#define MFMA(A, B, C) __builtin_amdgcn_mfma_f32_16x16x32_bf16((A), (B), (C), 0, 0, 0)

__device__ __forceinline__ unsigned short bf16r(float f) {
  unsigned int u = __builtin_bit_cast(unsigned int, f);
  u += 0x7FFFu + ((u >> 16) & 1u);   // round-to-nearest-even
  return (unsigned short)(u >> 16);
}
__device__ __forceinline__ float bf16f(unsigned short h) {
  unsigned int u = ((unsigned int)h) << 16;
  return __builtin_bit_cast(float, u);
}
__device__ __forceinline__ unsigned int pk2(float lo, float hi) {
  return (unsigned int)bf16r(lo) | ((unsigned int)bf16r(hi) << 16);
}
__device__ __forceinline__ float eluf(float v) {
  return v > 0.f ? v : (__expf(v) - 1.f);
}
__device__ __forceinline__ uint4 gather44(const short* A, const short* B, int s) {
  uint4 o;
  o.x = (unsigned int)(unsigned short)A[0 * s] |
        ((unsigned int)(unsigned short)A[1 * s] << 16);
  o.y = (unsigned int)(unsigned short)A[2 * s] |
        ((unsigned int)(unsigned short)A[3 * s] << 16);
  o.z = (unsigned int)(unsigned short)B[0 * s] |
        ((unsigned int)(unsigned short)B[1 * s] << 16);
  o.w = (unsigned int)(unsigned short)B[2 * s] |
        ((unsigned int)(unsigned short)B[3 * s] << 16);
  return o;
}

// ---------------- K0: weight prep (LDS transpose) ----------------
// w1 fp32 [l][n][d][e] (2,64,64,128)  -> w1t bf16 [l*64+n][e][d-slot]
// w2 fp32 [l][n][e][d'] (2,64,128,64) -> w2t bf16 [l*64+n][d'][e-slot]
// For ln>=64 (layer 1) the k-axis slots are pi32-permuted:
//   slot c holds k = (c&~31) + ( (c&7)<4 ? 4*((c>>3)&3)+(c&7) : 16+4*((c>>3)&3)+(c&7)-4 )
// matching the lane k-coverage of the MFMA-transposed fragments in k2.
__global__ __launch_bounds__(256) void k0_prep(const float* __restrict__ w1,
                                               const float* __restrict__ w2,
                                               short* __restrict__ w1t,
                                               short* __restrict__ w2t) {
  __shared__ __align__(16) short T[128 * 72];   // phase A uses [64][136] = 8704 shorts
  const int t  = threadIdx.x;
  const int ln = blockIdx.x >> 1;
  const bool pm = (ln >= 64);
  if ((blockIdx.x & 1) == 0) {
    // ---- w1 [64 d][128 e] -> w1t [e][d-slot] ----
    const float* src = w1 + (size_t)ln * 8192 + t * 32;
    const int d = t >> 2, e0 = (t & 3) * 32;
#pragma unroll
    for (int u = 0; u < 32; u += 2) {
      *(unsigned int*)&T[d * 136 + e0 + u] = pk2(src[u], src[u + 1]);
    }
    __syncthreads();
    const int e = t >> 1, d0 = (t & 1) * 32;
    short* dst = w1t + (size_t)ln * 8192 + e * 64 + d0;
#pragma unroll
    for (int k = 0; k < 4; ++k) {
      const int ta = d0 + (pm ? 4 * k : 8 * k);
      const int tb = d0 + (pm ? 16 + 4 * k : 8 * k + 4);
      *(uint4*)(dst + k * 8) = gather44(&T[ta * 136 + e], &T[tb * 136 + e], 136);
    }
  } else {
    // ---- w2 [128 e][64 d'] -> w2t [d'][e-slot] ----
    const float* src = w2 + (size_t)ln * 8192 + t * 32;
    const int e = t >> 1, d0 = (t & 1) * 32;
#pragma unroll
    for (int u = 0; u < 32; u += 2) {
      *(unsigned int*)&T[e * 72 + d0 + u] = pk2(src[u], src[u + 1]);
    }
    __syncthreads();
    const int dp = t >> 2, e0 = (t & 3) * 32;
    short* dst = w2t + (size_t)ln * 8192 + dp * 128 + e0;
#pragma unroll
    for (int k = 0; k < 4; ++k) {
      const int ta = e0 + (pm ? 4 * k : 8 * k);
      const int tb = e0 + (pm ? 16 + 4 * k : 8 * k + 4);
      *(uint4*)(dst + k * 8) = gather44(&T[ta * 72 + dp], &T[tb * 72 + dp], 72);
    }
  }
}

// ---------------- K1: layer 0 facto (unchanged, verified) ----------------
// WG = (n-pair x 64 rows), 4 waves. A-frags hoisted.
// y1 layout: [row>>4][n][j][row&15] bf16 -> stores are fully contiguous 512B runs.
__global__ __launch_bounds__(256) void k1_layer0(
    const float* __restrict__ x,
    const short* __restrict__ w1t, const short* __restrict__ w2t,
    const float* __restrict__ b1,  const float* __restrict__ b2,
    short* __restrict__ y1) {
  __shared__ __align__(16) short hst[4][2][16][72];
  const int tid  = threadIdx.x;
  const int lane = tid & 63;
  const int wv   = tid >> 6;
  const int il   = lane & 15;
  const int q    = lane >> 4;
  const int npair   = blockIdx.x & 31;
  const int rowtile = blockIdx.x >> 5;
  const int n  = npair * 2 + (wv & 1);
  const int r0 = rowtile * 64 + (wv >> 1) * 32;     // 32-row aligned

  const short* w1n = w1t + (size_t)n * 8192;
  const short* w2n = w2t + (size_t)n * 8192;
  const float* b1n = b1 + n * 128;
  const float* b2n = b2 + n * 64;

  // hoisted A-frags: load + convert x once
  short8 a[2][2];   // [ks][Mt]
#pragma unroll
  for (int Mt = 0; Mt < 2; ++Mt) {
#pragma unroll
    for (int ks = 0; ks < 2; ++ks) {
      const float* xp = x + (size_t)(r0 + Mt * 16 + il) * 4096 + n * 64 + ks * 32 + q * 8;
      floatx4 f0 = *(const floatx4*)xp;
      floatx4 f1 = *(const floatx4*)(xp + 4);
      short8 t;
#pragma unroll
      for (int u = 0; u < 4; ++u) { t[u] = (short)bf16r(f0[u]); t[4 + u] = (short)bf16r(f1[u]); }
      a[ks][Mt] = t;
    }
  }

  floatx4 acc2[2][4] = {};
  for (int hh = 0; hh < 2; ++hh) {
    floatx4 acc1[2][4] = {};
#pragma unroll
    for (int ks = 0; ks < 2; ++ks) {
#pragma unroll
      for (int nt = 0; nt < 4; ++nt) {
        short8 b = *(const short8*)(w1n + (hh * 64 + nt * 16 + il) * 64 + ks * 32 + q * 8);
        acc1[0][nt] = MFMA(a[ks][0], b, acc1[0][nt]);
        acc1[1][nt] = MFMA(a[ks][1], b, acc1[1][nt]);
      }
    }
    // epilogue 1: bias + ELU -> h stage (bf16)
#pragma unroll
    for (int nt = 0; nt < 4; ++nt) {
      float bias = b1n[hh * 64 + nt * 16 + il];
#pragma unroll
      for (int Mt = 0; Mt < 2; ++Mt)
#pragma unroll
        for (int rg = 0; rg < 4; ++rg) {
          float v = acc1[Mt][nt][rg] + bias;
          hst[wv][Mt][q * 4 + rg][nt * 16 + il] = (short)bf16r(eluf(v));
        }
    }
    asm volatile("s_waitcnt lgkmcnt(0)" ::: "memory");
#pragma unroll
    for (int ks2 = 0; ks2 < 2; ++ks2) {
      short8 a2[2];
      a2[0] = *(const short8*)&hst[wv][0][il][ks2 * 32 + q * 8];
      a2[1] = *(const short8*)&hst[wv][1][il][ks2 * 32 + q * 8];
#pragma unroll
      for (int nt2 = 0; nt2 < 4; ++nt2) {
        short8 b = *(const short8*)(w2n + (nt2 * 16 + il) * 128 + hh * 64 + ks2 * 32 + q * 8);
        acc2[0][nt2] = MFMA(a2[0], b, acc2[0][nt2]);
        acc2[1][nt2] = MFMA(a2[1], b, acc2[1][nt2]);
      }
    }
    asm volatile("s_waitcnt lgkmcnt(0)" ::: "memory");
  }
  // epilogue 2: bias + fp32 residual from x (L1/L2-hot),
  // store to y1[(row>>4)][n][j][row&15] -- contiguous 512B runs
#pragma unroll
  for (int Mt = 0; Mt < 2; ++Mt) {
    const int R0 = r0 + Mt * 16 + q * 4;
    const size_t nbase = ((size_t)((r0 + Mt * 16) >> 4) * 64 + n) * 64;
#pragma unroll
    for (int nt2 = 0; nt2 < 4; ++nt2) {
      const int j = nt2 * 16 + il;
      const float bias = b2n[j];
      float v0 = acc2[Mt][nt2][0] + bias + x[(size_t)(R0 + 0) * 4096 + n * 64 + j];
      float v1 = acc2[Mt][nt2][1] + bias + x[(size_t)(R0 + 1) * 4096 + n * 64 + j];
      float v2 = acc2[Mt][nt2][2] + bias + x[(size_t)(R0 + 2) * 4096 + n * 64 + j];
      float v3 = acc2[Mt][nt2][3] + bias + x[(size_t)(R0 + 3) * 4096 + n * 64 + j];
      uint2 pk;
      pk.x = pk2(v0, v1);
      pk.y = pk2(v2, v3);
      *(uint2*)(y1 + (nbase + j) * 16 + q * 4) = pk;
    }
  }
}

// ---------------- K2: layer 1 facto + inverse shuffle + fp32 out ----------------
// WG = 16 rows (granule G) x 16 m-blocks, 4 waves; wave owns 4 m's (sequential).
// z-transpose and h-transpose via permutation-B 16x16x32 MFMAs (verified intrinsic only):
//   A slots 0..3 hold the 4 r-values, slots 4..7 zero; B[k][n] = delta(k == (n>>2)*8+(n&3)).
//   => D lane(il,q) reg rg = src(r=il, col=C0+q*4+rg)  (exact: bf16 * 1.0 + 0).
// GEMMs use pi32-permuted layer-1 weights. Residual comes from the za load registers.
// Only LDS: out-staging yo[r][i][m] with strides RSTR=1156 / ISTR=18.
#define RSTR 1156
#define ISTR 18
__global__ __launch_bounds__(256) void k2_layer1_out(
    const short* __restrict__ y1,
    const short* __restrict__ w1t, const short* __restrict__ w2t,
    const float* __restrict__ b1,  const float* __restrict__ b2,
    float* __restrict__ out) {
  __shared__ __align__(16) short yo[16 * RSTR];   // 36992 B
  const int tid  = threadIdx.x;
  const int lane = tid & 63;
  const int wv   = tid >> 6;
  const int il   = lane & 15;
  const int q    = lane >> 4;
  const int G    = blockIdx.x & 511;        // 16-row granule
  const int m0   = (blockIdx.x >> 9) * 16;  // m window

  // permutation B-frag: lane (il,q) slot v holds B[k=q*8+v][n=il] = (v<4 && il==q*4+v)
  short8 pb;
#pragma unroll
  for (int v = 0; v < 8; ++v) pb[v] = (v < 4 && il == q * 4 + v) ? (short)0x3F80 : (short)0;
  const floatx4 zero4 = {0.f, 0.f, 0.f, 0.f};

#pragma unroll
  for (int mi = 0; mi < 4; ++mi) {
    const int ml = wv * 4 + mi;
    const int m  = m0 + ml;
    const short* w1m = w1t + (size_t)(64 + m) * 8192;
    const short* w2m = w2t + (size_t)(64 + m) * 8192;
    const float* b1m = b1 + (64 + m) * 128;
    const float* b2m = b2 + (64 + m) * 64;

    // ---- load z r-quads (also the residual!) ----
    // za[nt]: lane (il,q) reg u holds z2(r=q*4+u, d=nt*16+il)
    short4v za[4];
#pragma unroll
    for (int nt = 0; nt < 4; ++nt)
      za[nt] = *(const short4v*)(y1 + ((size_t)(G * 64 + nt * 16 + il) * 64 + m) * 16 + q * 4);

    // ---- z-transpose via perm-B MFMA: zd[nt] lane reg rg = z2(r=il, d=nt*16+q*4+rg) ----
    floatx4 zd[4];
#pragma unroll
    for (int nt = 0; nt < 4; ++nt) {
      short8 az = {za[nt][0], za[nt][1], za[nt][2], za[nt][3], 0, 0, 0, 0};
      zd[nt] = MFMA(az, pb, zero4);
    }
    // pack GEMM1 A-frags (pi32 slot order)
    short8 at[2];
#pragma unroll
    for (int ks = 0; ks < 2; ++ks) {
      uintx4 w;
      w[0] = pk2(zd[2 * ks][0], zd[2 * ks][1]);
      w[1] = pk2(zd[2 * ks][2], zd[2 * ks][3]);
      w[2] = pk2(zd[2 * ks + 1][0], zd[2 * ks + 1][1]);
      w[3] = pk2(zd[2 * ks + 1][2], zd[2 * ks + 1][3]);
      at[ks] = __builtin_bit_cast(short8, w);
    }

    floatx4 acc2[4] = {};
    uintx4 a2w[4];
#pragma unroll
    for (int hh = 0; hh < 2; ++hh) {
      floatx4 acc1[4] = {};
#pragma unroll
      for (int ks = 0; ks < 2; ++ks)
#pragma unroll
        for (int nt = 0; nt < 4; ++nt) {
          short8 b = *(const short8*)(w1m + (hh * 64 + nt * 16 + il) * 64 + ks * 32 + q * 8);
          acc1[nt] = MFMA(at[ks], b, acc1[nt]);
        }
      // bias + ELU -> bf16 -> h-transpose via perm-B MFMA -> GEMM2 A-frags (pi32 order)
#pragma unroll
      for (int nt = 0; nt < 4; ++nt) {
        const float bias = b1m[hh * 64 + nt * 16 + il];
        short8 ha = {(short)bf16r(eluf(acc1[nt][0] + bias)),
                     (short)bf16r(eluf(acc1[nt][1] + bias)),
                     (short)bf16r(eluf(acc1[nt][2] + bias)),
                     (short)bf16r(eluf(acc1[nt][3] + bias)),
                     0, 0, 0, 0};
        floatx4 hd = MFMA(ha, pb, zero4);
        // hd: lane holds h(r=il, e = hh*64 + nt*16 + q*4+rg)
        const int ks2 = hh * 2 + (nt >> 1);
        const int hf  = nt & 1;
        a2w[ks2][hf * 2 + 0] = pk2(hd[0], hd[1]);
        a2w[ks2][hf * 2 + 1] = pk2(hd[2], hd[3]);
      }
    }
#pragma unroll
    for (int ks2 = 0; ks2 < 4; ++ks2) {
      short8 af = __builtin_bit_cast(short8, a2w[ks2]);
#pragma unroll
      for (int nt2 = 0; nt2 < 4; ++nt2) {
        short8 b = *(const short8*)(w2m + (nt2 * 16 + il) * 128 + ks2 * 32 + q * 8);
        acc2[nt2] = MFMA(af, b, acc2[nt2]);
      }
    }
    // epilogue: bias + residual (from za regs, exact same bf16 values) -> yo
#pragma unroll
    for (int nt2 = 0; nt2 < 4; ++nt2) {
      const int i = nt2 * 16 + il;
      const float bias = b2m[i];
#pragma unroll
      for (int rg = 0; rg < 4; ++rg) {
        float val = acc2[nt2][rg] + bias + bf16f((unsigned short)za[nt2][rg]);
        yo[(q * 4 + rg) * RSTR + i * ISTR + ml] = (short)bf16r(val);
      }
    }
  }
  __syncthreads();

  // ---- flush: out[G*16+r][i*64 + m0 + mm] = yo[r][i][mm], fp32, 64B runs ----
  const int r  = tid & 15;
  const int i0 = (tid >> 4) * 4;
  float* orow = out + (size_t)(G * 16 + r) * 4096 + m0;
#pragma unroll
  for (int k = 0; k < 4; ++k) {
    const int i = i0 + k;
    const short* yr = &yo[r * RSTR + i * ISTR];
    float f[16];
#pragma unroll
    for (int j = 0; j < 8; ++j) {
      unsigned int w = *(const unsigned int*)(yr + 2 * j);
      f[2 * j]     = bf16f((unsigned short)(w & 0xffffu));
      f[2 * j + 1] = bf16f((unsigned short)(w >> 16));
    }
    float* op = orow + i * 64;
    *(floatx4*)(op + 0)  = (floatx4){f[0],  f[1],  f[2],  f[3]};
    *(floatx4*)(op + 4)  = (floatx4){f[4],  f[5],  f[6],  f[7]};
    *(floatx4*)(op + 8)  = (floatx4){f[8],  f[9],  f[10], f[11]};
    *(floatx4*)(op + 12) = (floatx4){f[12], f[13], f[14], f[15]};
  }
}

extern "C" void kernel_launch(void* const* d_in, const int* in_sizes, int n_in,
                              void* d_out, int out_size, void* d_ws, size_t ws_size,
                              hipStream_t stream) {
  const float* x  = (const float*)d_in[0];
  const float* w1 = (const float*)d_in[1];
  const float* b1 = (const float*)d_in[2];
  const float* w2 = (const float*)d_in[3];
  const float* b2 = (const float*)d_in[4];
  float* out = (float*)d_out;

  short* w1t = (short*)d_ws;
  short* w2t = w1t + (1u << 20);
  short* y1  = w2t + (1u << 20);

  hipLaunchKernelGGL(k0_prep,       dim3(256),  dim3(256), 0, stream, w1, w2, w1t, w2t);
  hipLaunchKernelGGL(k1_layer0,     dim3(4096), dim3(256), 0, stream, x, w1t, w2t, b1, b2, y1);
  hipLaunchKernelGGL(k2_layer1_out, dim3(2048), dim3(256), 0, stream, y1, w1t, w2t, b1, b2, out);
}